// Round 14
// baseline (165.483 us; speedup 1.0000x reference)
//
#include <hip/hip_runtime.h>
#include <math.h>

#define NN 50000
#define NE 800000
#define DD 64
#define FC_BLOCKS 782  // ceil(NN/64)
#define N4 12503       // int4s of deg zeroed
#define ZB 49          // ceil(N4/256) zero blocks appended to fc1 grid

typedef __attribute__((ext_vector_type(8))) short short8v;
typedef __attribute__((ext_vector_type(4))) float floatx4;
typedef unsigned short ushort;

__device__ __forceinline__ unsigned bf16r(float x) {  // round-to-nearest-even bf16
  unsigned u = __float_as_uint(x);
  return (u + 0x7fffu + ((u >> 16) & 1u)) >> 16;
}
__device__ __forceinline__ float b2f(ushort u) {
  return __uint_as_float((unsigned)u << 16);
}

// -------------------- kernels --------------------

// histogram dst degrees, 4 edges/thread; per-edge position captured as uchar
__global__ void k_hist(const int4* __restrict__ dst4, int* __restrict__ deg,
                       uchar4* __restrict__ pos4) {
  int q = blockIdx.x * 256 + threadIdx.x;
  if (q >= NE / 4) return;
  int4 dn = dst4[q];
  uchar4 p;
  p.x = (unsigned char)atomicAdd(&deg[dn.x], 1);
  p.y = (unsigned char)atomicAdd(&deg[dn.y], 1);
  p.z = (unsigned char)atomicAdd(&deg[dn.z], 1);
  p.w = (unsigned char)atomicAdd(&deg[dn.w], 1);
  pos4[q] = p;
}

// single-kernel exclusive scan: each block redundantly pre-reduces its base
// (sum deg[0..blockStart)), then local shuffle-scan.
__global__ void k_scan(const int* __restrict__ deg, int* __restrict__ rp) {
  __shared__ int wred[16];
  __shared__ int woff[16];
  __shared__ int sbase;
  int t = threadIdx.x;
  int lane = t & 63, w = t >> 6;
  int blockStart = blockIdx.x << 10;
  int acc = 0;
  for (int i = t; i < blockStart; i += 1024) acc += deg[i];
#pragma unroll
  for (int off = 32; off > 0; off >>= 1) acc += __shfl_xor(acc, off, 64);
  if (lane == 0) wred[w] = acc;
  __syncthreads();
  if (t == 0) {
    int b = 0;
#pragma unroll
    for (int k = 0; k < 16; ++k) b += wred[k];
    sbase = b;
  }
  int i = blockStart + t;
  int v = (i < NN) ? deg[i] : 0;
  int sc = v;  // inclusive within wave
#pragma unroll
  for (int off = 1; off < 64; off <<= 1) {
    int x = __shfl_up(sc, off, 64);
    if (lane >= off) sc += x;
  }
  if (lane == 63) woff[w] = sc;
  __syncthreads();
  if (t < 16) {
    int ws = woff[t];
    int s2 = ws;
#pragma unroll
    for (int off = 1; off < 16; off <<= 1) {
      int x = __shfl_up(s2, off, 64);
      if (t >= off) s2 += x;
    }
    woff[t] = s2 - ws;  // exclusive wave offset
  }
  __syncthreads();
  if (i <= NN) rp[i] = sc - v + woff[w] + sbase;  // rp[NN] lands as NE
}

// atomic-free scatter, 4 edges/thread; ssrc stored as ushort (src < 65536)
__global__ void k_scatter(const int4* __restrict__ src4, const int4* __restrict__ dst4,
                          const int* __restrict__ rp, const uchar4* __restrict__ pos4,
                          ushort* __restrict__ ssrc) {
  int q = blockIdx.x * 256 + threadIdx.x;
  if (q >= NE / 4) return;
  int4 s = src4[q], dn = dst4[q];
  uchar4 p = pos4[q];
  ssrc[rp[dn.x] + p.x] = (ushort)s.x;
  ssrc[rp[dn.y] + p.y] = (ushort)s.y;
  ssrc[rp[dn.z] + p.z] = (ushort)s.z;
  ssrc[rp[dn.w] + p.w] = (ushort)s.w;
}

// MFMA FC. HBF16: h is bf16 ushort rows (direct frag loads); else f32 + ids,
// and the f32 h row is also written to out cols 0..63 (h0 passthrough).
template <bool HBF16>
__global__ void __launch_bounds__(256) k_fc_mfma(const void* __restrict__ hp,
                                                 const int* __restrict__ ids,
                                                 const float* __restrict__ W,
                                                 const float* __restrict__ b,
                                                 unsigned* __restrict__ hfb,
                                                 float* __restrict__ out0,
                                                 int4* __restrict__ zbuf, int n4) {
  if (blockIdx.x >= FC_BLOCKS) {  // zero-deg tail blocks (layer 1 only)
    int i = (blockIdx.x - FC_BLOCKS) * 256 + threadIdx.x;
    if (i < n4) zbuf[i] = make_int4(0, 0, 0, 0);
    return;
  }
  int lane = threadIdx.x & 63;
  int wid = threadIdx.x >> 6;
  int nbase = blockIdx.x * 64 + wid * 16;
  if (nbase >= NN) return;
  int r16 = lane & 15, kg = lane >> 4;

  int rowA = (!HBF16 && ids) ? ids[nbase + r16] : (nbase + r16);
  short8v afr[2];
  if (HBF16) {
    const ushort* hrow = (const ushort*)hp + (size_t)rowA * DD;
#pragma unroll
    for (int kt = 0; kt < 2; ++kt)
      afr[kt] = *(const short8v*)(hrow + kt * 32 + kg * 8);
  } else {
    const float* hrow = (const float*)hp + (size_t)rowA * DD;
#pragma unroll
    for (int kt = 0; kt < 2; ++kt) {
      int k0 = kt * 32 + kg * 8;
#pragma unroll
      for (int i = 0; i < 8; ++i) afr[kt][i] = (short)bf16r(hrow[k0 + i]);
    }
  }
  int orow[4];
#pragma unroll
  for (int r = 0; r < 4; ++r) {
    int node = nbase + kg * 4 + r;
    orow[r] = (!HBF16 && ids) ? ids[node] : node;
  }
  short8v bfr[4][2];
#pragma unroll
  for (int dt = 0; dt < 4; ++dt) {
    const float* wrow = W + (dt * 16 + r16) * 64;
#pragma unroll
    for (int kt = 0; kt < 2; ++kt) {
      int k0 = kt * 32 + kg * 8;
#pragma unroll
      for (int i = 0; i < 8; ++i) bfr[dt][kt][i] = (short)bf16r(wrow[k0 + i]);
    }
  }
#pragma unroll
  for (int dt = 0; dt < 4; ++dt) {
    floatx4 acc = {0.f, 0.f, 0.f, 0.f};
    acc = __builtin_amdgcn_mfma_f32_16x16x32_bf16(afr[0], bfr[dt][0], acc, 0, 0, 0);
    acc = __builtin_amdgcn_mfma_f32_16x16x32_bf16(afr[1], bfr[dt][1], acc, 0, 0, 0);
    int d = dt * 16 + r16;
    float bias = b[d];
#pragma unroll
    for (int r = 0; r < 4; ++r) {
      int node = nbase + kg * 4 + r;
      float feat = fmaxf(acc[r] + bias, 0.f);
      unsigned lo;
      if (HBF16) {
        lo = (unsigned)((const ushort*)hp)[(size_t)orow[r] * DD + d];
      } else {
        float hv = ((const float*)hp)[(size_t)orow[r] * DD + d];
        out0[(size_t)node * 192 + d] = hv;  // h0 passthrough (free here)
        lo = bf16r(hv);
      }
      hfb[node * DD + d] = lo | (bf16r(feat) << 16);
    }
  }
}

// One wave per dst node (R9-proven structure). Wave-uniform work on SALU;
// ssrc is ushort-packed: one s_load_dword covers two edge indices (hi/lo
// select on SALU). Softmax w/o max-subtraction (|e| bounded). 8-wide batches;
// clamped dup slots corrected with the last batch's slot-7 values (free).
// FINAL fuses l2-normalize(h2) and l2-normalize(h1) (h0 written by fc1).
template <bool FINAL, bool HBF16>
__global__ void __launch_bounds__(256)
k_edge_t(const unsigned* __restrict__ hfb, const void* __restrict__ hp,
         const int* __restrict__ ids, const int* __restrict__ rp,
         const unsigned* __restrict__ ss2, void* __restrict__ outp,
         const ushort* __restrict__ h1b) {
  int d = threadIdx.x & 63;
  int node = __builtin_amdgcn_readfirstlane(blockIdx.x * 4 + (threadIdx.x >> 6));
  int beg = __builtin_amdgcn_readfirstlane(rp[node]);
  int end = __builtin_amdgcn_readfirstlane(rp[node + 1]);
  int hrow = (!HBF16 && ids) ? __builtin_amdgcn_readfirstlane(ids[node]) : node;
  float hdr = HBF16 ? b2f(((const ushort*)hp)[(size_t)hrow * DD + d])
                    : ((const float*)hp)[(size_t)hrow * DD + d];
  float hd = hdr * 1.44269504f;  // exp(x)=exp2(x*log2e)
  const unsigned* hfb_d = hfb + d;
  int deg = end - beg;
  int lim = end - 1;
  float ss = 0.f, aa = 0.f;
  if (deg > 0) {
    float s[8] = {0.f, 0.f, 0.f, 0.f, 0.f, 0.f, 0.f, 0.f};
    float a[8] = {0.f, 0.f, 0.f, 0.f, 0.f, 0.f, 0.f, 0.f};
    float e7 = 0.f, f7 = 0.f;
    for (int p = beg; p < end; p += 8) {
      unsigned v[8];
#pragma unroll
      for (int j = 0; j < 8; ++j) {
        int q = p + j;
        q = (q > lim) ? lim : q;  // SALU clamp
        unsigned pr = __builtin_amdgcn_readfirstlane(ss2[q >> 1]);
        int idx = (q & 1) ? (int)(pr >> 16) : (int)(pr & 0xffffu);
        v[j] = hfb_d[(size_t)idx * DD];
      }
#pragma unroll
      for (int j = 0; j < 8; ++j) {
        float hv = __uint_as_float(v[j] << 16);
        float fv = __uint_as_float(v[j] & 0xffff0000u);
        float ex = __builtin_amdgcn_exp2f(hv * hd);
        s[j] += ex;
        a[j] = fmaf(fv, ex, a[j]);
        if (j == 7) { e7 = ex; f7 = fv; }  // last batch's values survive
      }
    }
    ss = ((s[0] + s[1]) + (s[2] + s[3])) + ((s[4] + s[5]) + (s[6] + s[7]));
    aa = ((a[0] + a[1]) + (a[2] + a[3])) + ((a[4] + a[5]) + (a[6] + a[7]));
    int dups = (8 - (deg & 7)) & 7;
    if (dups) {  // uniform branch; slot-7 of last batch was the lim row
      float fd = (float)dups;
      ss = fmaf(-fd, e7, ss);
      aa = fmaf(-fd * f7, e7, aa);
    }
  }
  float hval = (deg > 0) ? aa / ss : 0.f;
  if (!FINAL) {
    ((ushort*)outp)[(size_t)node * DD + d] = (ushort)bf16r(hval);  // h1 as bf16
  } else {
    float* out = (float*)outp;
    float v1 = b2f(h1b[(size_t)node * DD + d]);
    float s1 = v1 * v1, s2 = hval * hval;
#pragma unroll
    for (int off = 32; off > 0; off >>= 1) {
      s1 += __shfl_xor(s1, off, 64);
      s2 += __shfl_xor(s2, off, 64);
    }
    out[node * 192 + 64 + d] = v1 / fmaxf(sqrtf(s1), 1e-12f);
    out[node * 192 + 128 + d] = hval / fmaxf(sqrtf(s2), 1e-12f);
  }
}

// -------------------- launch --------------------

extern "C" void kernel_launch(void* const* d_in, const int* in_sizes, int n_in,
                              void* d_out, int out_size, void* d_ws, size_t ws_size,
                              hipStream_t stream) {
  const int* node_ids = (const int*)d_in[0];
  const int* src = (const int*)d_in[1];
  const int* dst = (const int*)d_in[2];
  const float* emb = (const float*)d_in[3];
  const float* W0 = (const float*)d_in[4];
  const float* b0 = (const float*)d_in[5];
  const float* W1 = (const float*)d_in[8];
  const float* b1 = (const float*)d_in[9];
  float* out = (float*)d_out;

  size_t o = 0;
  auto alloc = [&](size_t nbytes) {
    char* p = (char*)d_ws + o;
    o += (nbytes + 255) & ~(size_t)255;
    return (void*)p;
  };
  ushort* h1b = (ushort*)alloc((size_t)NN * DD * 2);  // h1 stored as bf16
  unsigned* hfb = (unsigned*)alloc((size_t)NN * DD * 4);
  int* deg = (int*)alloc((size_t)N4 * 16);
  int* rp = (int*)alloc((size_t)(NN + 1) * 4);
  ushort* ssrc = (ushort*)alloc((size_t)NE * 2);  // packed edge src indices
  unsigned char* pos = (unsigned char*)alloc((size_t)NE);
  (void)o; (void)ws_size; (void)in_sizes; (void)n_in; (void)out_size;

  // layer-1 FC (independent of CSR) + h0 passthrough + deg zeroing tail blocks
  k_fc_mfma<false><<<FC_BLOCKS + ZB, 256, 0, stream>>>(emb, node_ids, W0, b0, hfb,
                                                       out, (int4*)deg, N4);
  k_hist<<<(NE / 4 + 255) / 256, 256, 0, stream>>>((const int4*)dst, deg,
                                                   (uchar4*)pos);
  int NB = (NN + 1023) / 1024;  // 49
  k_scan<<<NB, 1024, 0, stream>>>(deg, rp);
  k_scatter<<<(NE / 4 + 255) / 256, 256, 0, stream>>>(
      (const int4*)src, (const int4*)dst, rp, (const uchar4*)pos, ssrc);

  // layer 1 aggregation -> h1 (bf16)
  k_edge_t<false, false><<<(NN + 3) / 4, 256, 0, stream>>>(
      hfb, emb, node_ids, rp, (const unsigned*)ssrc, h1b, nullptr);
  // layer 2 FC (bf16 input, direct frag loads)
  k_fc_mfma<true><<<FC_BLOCKS, 256, 0, stream>>>(h1b, nullptr, W1, b1, hfb,
                                                 nullptr, nullptr, 0);
  // layer 2 aggregation + fused finalize (norm h2, norm h1)
  k_edge_t<true, true><<<(NN + 3) / 4, 256, 0, stream>>>(
      hfb, h1b, nullptr, rp, (const unsigned*)ssrc, out, h1b);
}